// Round 1
// baseline (311.168 us; speedup 1.0000x reference)
//
#include <hip/hip_runtime.h>
#include <hip/hip_bf16.h>
#include <stdint.h>

// Problem constants (fixed by setup_inputs): B=D=O=4096, m=2048
#define D_DIM     4096
#define MB        2048   // M_BUCKETS = K of the GEMM
#define NROWS     4096   // B == O == 4096
#define K_DIM     MB

typedef __bf16 bf16x8 __attribute__((ext_vector_type(8)));
typedef float  floatx4 __attribute__((ext_vector_type(4)));

// ---------------------------------------------------------------------------
// async global->LDS, 16B per lane. LDS dest is wave-uniform base + lane*16;
// passing &lds[t*8] per lane is consistent with that mapping (m97 pattern).
// ---------------------------------------------------------------------------
__device__ __forceinline__ void gld_lds16(const void* g, void* l) {
    __builtin_amdgcn_global_load_lds(
        (const __attribute__((address_space(1))) unsigned int*)g,
        (__attribute__((address_space(3))) unsigned int*)l,
        16, 0, 0);
}

// ---------------------------------------------------------------------------
// Kernel 1: invert hash_idx -> CSR (bucket -> column list). One block.
// ---------------------------------------------------------------------------
__global__ __launch_bounds__(256) void build_csr(
    const int* __restrict__ hash_idx,
    int* __restrict__ csr_off,   // [MB+1]
    int* __restrict__ csr_col)   // [D_DIM]
{
    __shared__ int cnt[MB];
    __shared__ int scan[MB];
    const int t = threadIdx.x;

    for (int k = t; k < MB; k += 256) cnt[k] = 0;
    __syncthreads();
    for (int j = t; j < D_DIM; j += 256) atomicAdd(&cnt[hash_idx[j]], 1);
    __syncthreads();
    for (int k = t; k < MB; k += 256) scan[k] = cnt[k];
    __syncthreads();
    // Hillis-Steele inclusive scan over 2048 entries, 256 threads x 8 elems
    for (int stride = 1; stride < MB; stride <<= 1) {
        int vals[8];
        #pragma unroll
        for (int i = 0; i < 8; ++i) {
            int k = t + 256 * i;
            vals[i] = (k >= stride) ? scan[k - stride] : 0;
        }
        __syncthreads();
        #pragma unroll
        for (int i = 0; i < 8; ++i) scan[t + 256 * i] += vals[i];
        __syncthreads();
    }
    // exclusive offsets
    for (int k = t; k < MB; k += 256) csr_off[k] = scan[k] - cnt[k];
    if (t == 0) csr_off[MB] = scan[MB - 1];
    // reuse cnt as scatter cursors (= exclusive offsets)
    for (int k = t; k < MB; k += 256) cnt[k] = scan[k] - cnt[k];
    __syncthreads();
    for (int j = t; j < D_DIM; j += 256) {
        int k = hash_idx[j];
        int pos = atomicAdd(&cnt[k], 1);
        csr_col[pos] = j;  // order within bucket irrelevant (commutative add)
    }
}

// ---------------------------------------------------------------------------
// Kernel 2: countsketch via CSR gather. One block per row (input then weight).
// Stage row*sign in LDS (coalesced float4), gather per-bucket, write bf16.
// ---------------------------------------------------------------------------
__global__ __launch_bounds__(256) void sketch_kernel(
    const float* __restrict__ input,    // [4096][4096]
    const float* __restrict__ weight,   // [4096][4096]
    const float* __restrict__ rand_sgn, // [4096]
    const int* __restrict__ csr_off,
    const int* __restrict__ csr_col,
    __hip_bfloat16* __restrict__ sk_in, // [4096][2048]
    __hip_bfloat16* __restrict__ sk_w)  // [4096][2048]
{
    __shared__ float row[D_DIM];
    const int b = blockIdx.x;
    const bool is_w = (b >= NROWS);
    const int r = is_w ? (b - NROWS) : b;
    const float* src = (is_w ? weight : input) + (size_t)r * D_DIM;
    __hip_bfloat16* dst = (is_w ? sk_w : sk_in) + (size_t)r * MB;
    const int t = threadIdx.x;

    const float4* src4 = (const float4*)src;
    const float4* sgn4 = (const float4*)rand_sgn;
    #pragma unroll
    for (int i = 0; i < 4; ++i) {
        int idx = t + 256 * i;             // 1024 float4 per row
        float4 x = src4[idx], s = sgn4[idx];
        row[4 * idx + 0] = x.x * s.x;
        row[4 * idx + 1] = x.y * s.y;
        row[4 * idx + 2] = x.z * s.z;
        row[4 * idx + 3] = x.w * s.w;
    }
    __syncthreads();

    #pragma unroll
    for (int i = 0; i < 8; ++i) {
        int k = t + 256 * i;               // coalesced bf16 writes across lanes
        int o0 = csr_off[k], o1 = csr_off[k + 1];
        float sum = 0.f;
        for (int p = o0; p < o1; ++p) sum += row[csr_col[p]];
        dst[k] = __float2bfloat16(sum);
    }
}

// ---------------------------------------------------------------------------
// Kernel 3: C[m][n] = sum_k A[m][k]*B[n][k] + bias[n]   (bf16 MFMA, fp32 out)
// m97 structure: 128x128 tile, BK=32, 4 waves * (4x4 16x16 tiles),
// global_load_lds width=16, unpadded LDS, 2-barrier K-loop.
// ---------------------------------------------------------------------------
__global__ __launch_bounds__(256) void gemm_bt_bias(
    const __hip_bfloat16* __restrict__ A,   // [4096][2048]
    const __hip_bfloat16* __restrict__ B,   // [4096][2048]
    const float* __restrict__ bias,         // [4096]
    float* __restrict__ C)                  // [4096][4096]
{
    __shared__ __align__(16) __hip_bfloat16 lA[128 * 32];
    __shared__ __align__(16) __hip_bfloat16 lB[128 * 32];

    const int t = threadIdx.x;
    const int lane = t & 63;
    const int wid  = t >> 6;
    const int warpM = wid & 1, warpN = wid >> 1;
    const int quad = lane >> 4;     // 0..3
    const int mrow = lane & 15;     // row-in-tile for A frag, col for B frag / C
    const int rowBase = blockIdx.y * 128;
    const int colBase = blockIdx.x * 128;

    // staging map: thread t loads 16B = 8 bf16; row = t/4 (0..63), col = (t%4)*8
    const int sr = t >> 2;
    const int sc = (t & 3) << 3;
    const __hip_bfloat16* gA = A + (size_t)(rowBase + sr) * K_DIM + sc;
    const __hip_bfloat16* gB = B + (size_t)(colBase + sr) * K_DIM + sc;
    __hip_bfloat16* sA = &lA[t * 8];
    __hip_bfloat16* sB = &lB[t * 8];

    floatx4 acc[4][4];
    const floatx4 zero = {0.f, 0.f, 0.f, 0.f};
    #pragma unroll
    for (int i = 0; i < 4; ++i)
        #pragma unroll
        for (int j = 0; j < 4; ++j) acc[i][j] = zero;

    for (int kb = 0; kb < K_DIM; kb += 32) {
        gld_lds16(gA + kb,                         sA);
        gld_lds16(gA + (size_t)64 * K_DIM + kb,    sA + 2048);
        gld_lds16(gB + kb,                         sB);
        gld_lds16(gB + (size_t)64 * K_DIM + kb,    sB + 2048);
        __syncthreads();   // drains vmcnt before barrier (compiler-inserted)

        bf16x8 af[4], bfr[4];
        #pragma unroll
        for (int i = 0; i < 4; ++i) {
            af[i]  = *(const bf16x8*)&lA[(warpM * 64 + i * 16 + mrow) * 32 + quad * 8];
            bfr[i] = *(const bf16x8*)&lB[(warpN * 64 + i * 16 + mrow) * 32 + quad * 8];
        }
        #pragma unroll
        for (int i = 0; i < 4; ++i)
            #pragma unroll
            for (int j = 0; j < 4; ++j)
                acc[i][j] = __builtin_amdgcn_mfma_f32_16x16x32_bf16(
                    af[i], bfr[j], acc[i][j], 0, 0, 0);
        __syncthreads();   // all ds_reads done before next-iter staging
    }

    // epilogue: C/D layout col=lane&15, row=quad*4+reg  [measured m89/m91]
    float bj[4];
    #pragma unroll
    for (int j = 0; j < 4; ++j) bj[j] = bias[colBase + warpN * 64 + j * 16 + mrow];
    #pragma unroll
    for (int i = 0; i < 4; ++i) {
        int m0 = rowBase + warpM * 64 + i * 16 + quad * 4;
        #pragma unroll
        for (int j = 0; j < 4; ++j) {
            int n = colBase + warpN * 64 + j * 16 + mrow;
            #pragma unroll
            for (int p = 0; p < 4; ++p)
                C[(size_t)(m0 + p) * NROWS + n] = acc[i][j][p] + bj[j];
        }
    }
}

// ---------------------------------------------------------------------------
extern "C" void kernel_launch(void* const* d_in, const int* in_sizes, int n_in,
                              void* d_out, int out_size, void* d_ws, size_t ws_size,
                              hipStream_t stream) {
    const float* input  = (const float*)d_in[0];
    const float* weight = (const float*)d_in[1];
    const float* bias   = (const float*)d_in[2];
    const int*   hidx   = (const int*)d_in[3];
    const float* sgn    = (const float*)d_in[4];
    float* out = (float*)d_out;

    // workspace layout: sk_in 16MB | sk_w 16MB | csr_off | csr_col  (~33.6MB)
    char* ws = (char*)d_ws;
    __hip_bfloat16* sk_in = (__hip_bfloat16*)ws;
    __hip_bfloat16* sk_w  = (__hip_bfloat16*)(ws + (size_t)16 * 1024 * 1024);
    int* csr_off = (int*)(ws + (size_t)32 * 1024 * 1024);
    int* csr_col = csr_off + 2064;   // 16B-aligned tail

    build_csr<<<1, 256, 0, stream>>>(hidx, csr_off, csr_col);
    sketch_kernel<<<2 * NROWS, 256, 0, stream>>>(input, weight, sgn,
                                                 csr_off, csr_col, sk_in, sk_w);
    gemm_bt_bias<<<dim3(32, 32), 256, 0, stream>>>(sk_in, sk_w, bias, out);
}

// Round 2
// 268.616 us; speedup vs baseline: 1.1584x; 1.1584x over previous
//
#include <hip/hip_runtime.h>
#include <hip/hip_bf16.h>
#include <stdint.h>

// Problem constants (fixed by setup_inputs): B=D=O=4096, m=2048
#define D_DIM     4096
#define MB        2048   // M_BUCKETS = K of the GEMM
#define NROWS     4096   // B == O == 4096
#define K_DIM     MB

typedef __bf16 bf16x8 __attribute__((ext_vector_type(8)));
typedef float  floatx4 __attribute__((ext_vector_type(4)));

// async global->LDS, 16B per lane (wave-uniform base + lane*16 semantics)
__device__ __forceinline__ void gld_lds16(const void* g, void* l) {
    __builtin_amdgcn_global_load_lds(
        (const __attribute__((address_space(1))) unsigned int*)g,
        (__attribute__((address_space(3))) unsigned int*)l,
        16, 0, 0);
}

// ---------------------------------------------------------------------------
// Kernel 1: invert hash_idx into packed CSR:
//   desc[k]  = (start << 5) | count   (count<=31; P(Poisson(2)>=32) ~ 1e-24)
//   cols16[] = column indices bucket-by-bucket (uint16)
// One block.
// ---------------------------------------------------------------------------
__global__ __launch_bounds__(256) void build_csr(
    const int* __restrict__ hash_idx,
    unsigned int* __restrict__ desc,       // [MB]
    unsigned short* __restrict__ cols16)   // [D_DIM]
{
    __shared__ int cnt[MB];
    __shared__ int scan[MB];
    const int t = threadIdx.x;

    for (int k = t; k < MB; k += 256) cnt[k] = 0;
    __syncthreads();
    for (int j = t; j < D_DIM; j += 256) atomicAdd(&cnt[hash_idx[j]], 1);
    __syncthreads();
    for (int k = t; k < MB; k += 256) scan[k] = cnt[k];
    __syncthreads();
    // Hillis-Steele inclusive scan, 2048 entries, 256 threads x 8
    for (int stride = 1; stride < MB; stride <<= 1) {
        int vals[8];
        #pragma unroll
        for (int i = 0; i < 8; ++i) {
            int k = t + 256 * i;
            vals[i] = (k >= stride) ? scan[k - stride] : 0;
        }
        __syncthreads();
        #pragma unroll
        for (int i = 0; i < 8; ++i) scan[t + 256 * i] += vals[i];
        __syncthreads();
    }
    // desc + scatter cursors (cnt becomes cursor = exclusive offset)
    for (int k = t; k < MB; k += 256) {
        int excl = scan[k] - cnt[k];
        desc[k] = ((unsigned)excl << 5) | (unsigned)cnt[k];
        cnt[k] = excl;
    }
    __syncthreads();
    for (int j = t; j < D_DIM; j += 256) {
        int k = hash_idx[j];
        int pos = atomicAdd(&cnt[k], 1);
        cols16[pos] = (unsigned short)j;   // in-bucket order irrelevant
    }
}

// ---------------------------------------------------------------------------
// Kernel 2: countsketch, 2 rows per block (contiguous). All-gather from LDS:
//   rows (with sign folded) staged as one linear float4 stream,
//   cols16 preloaded via global_load_lds, desc read coalesced.
// ---------------------------------------------------------------------------
__global__ __launch_bounds__(256) void sketch2(
    const float* __restrict__ input,    // [4096][4096]
    const float* __restrict__ weight,   // [4096][4096]
    const float* __restrict__ rand_sgn, // [4096]
    const unsigned int* __restrict__ desc,
    const unsigned short* __restrict__ cols16,
    __hip_bfloat16* __restrict__ sk_in, // [4096][2048]
    __hip_bfloat16* __restrict__ sk_w)  // [4096][2048]
{
    __shared__ float rowAB[2 * D_DIM];                         // 32 KB
    __shared__ __align__(16) unsigned short cols[D_DIM];       // 8 KB
    const int b = blockIdx.x;
    const bool is_w = (b >= NROWS / 2);
    const int pr = is_w ? (b - NROWS / 2) : b;                 // row-pair index
    const float* src = (is_w ? weight : input) + (size_t)pr * 2 * D_DIM;
    __hip_bfloat16* dst = (is_w ? sk_w : sk_in) + (size_t)pr * 2 * MB;
    const int t = threadIdx.x;

    // preload cols16 (8 KB) straight into LDS
    gld_lds16(cols16 + t * 8,         &cols[t * 8]);
    gld_lds16(cols16 + (t + 256) * 8, &cols[(t + 256) * 8]);

    // stage 2 contiguous rows * sign (8192 floats = 2048 float4)
    const float4* s4 = (const float4*)src;
    const float4* g4 = (const float4*)rand_sgn;
    float4* r4 = (float4*)rowAB;
    #pragma unroll
    for (int p = 0; p < 8; ++p) {
        int idx = t + 256 * p;
        float4 x = s4[idx];
        float4 g = g4[idx & 1023];
        float4 y; y.x = x.x * g.x; y.y = x.y * g.y; y.z = x.z * g.z; y.w = x.w * g.w;
        r4[idx] = y;
    }
    __syncthreads();   // also drains the global_load_lds (vmcnt before barrier)

    #pragma unroll
    for (int i = 0; i < 8; ++i) {
        int k = t + 256 * i;                 // coalesced desc load + bf16 stores
        unsigned d = desc[k];
        int st = (int)(d >> 5), c = (int)(d & 31);
        float s0 = 0.f, s1 = 0.f;
        for (int p = 0; p < c; ++p) {
            int j = cols[st + p];            // pure-LDS gather
            s0 += rowAB[j];
            s1 += rowAB[D_DIM + j];
        }
        dst[k]      = __float2bfloat16(s0);
        dst[MB + k] = __float2bfloat16(s1);
    }
}

// ---------------------------------------------------------------------------
// Kernel 3: C = A * B^T + bias, bf16 MFMA. 128x128 tile, BK=64 (32 MFMA per
// barrier pair), XOR-swizzled granule layout -> 2-way (free) LDS aliasing.
// slot(m,q) = m*8 + (q ^ (m&7));  granule = 8 bf16 = 16 B.
// ---------------------------------------------------------------------------
__global__ __launch_bounds__(256) void gemm_bt_bias(
    const __hip_bfloat16* __restrict__ A,   // [4096][2048]
    const __hip_bfloat16* __restrict__ B,   // [4096][2048]
    const float* __restrict__ bias,         // [4096]
    float* __restrict__ C)                  // [4096][4096]
{
    __shared__ __align__(16) __hip_bfloat16 lA[128 * 64];   // 16 KB
    __shared__ __align__(16) __hip_bfloat16 lB[128 * 64];   // 16 KB

    const int t = threadIdx.x;
    const int lane = t & 63;
    const int wid  = t >> 6;
    const int warpM = wid & 1, warpN = wid >> 1;
    const int quad = lane >> 4;     // 0..3
    const int mrow = lane & 15;
    const int rowBase = blockIdx.y * 128;
    const int colBase = blockIdx.x * 128;

    // staging: pass p stages granule G = t + 256p (G = LDS slot, linear).
    // slot G holds logical granule (m = G>>3, q = (G&7) ^ (m&7)).
    const __hip_bfloat16* gA[4];
    const __hip_bfloat16* gB[4];
    #pragma unroll
    for (int p = 0; p < 4; ++p) {
        int G = t + 256 * p;
        int m = G >> 3;
        int q = (G & 7) ^ (m & 7);
        gA[p] = A + (size_t)(rowBase + m) * K_DIM + q * 8;
        gB[p] = B + (size_t)(colBase + m) * K_DIM + q * 8;
    }
    __hip_bfloat16* sA = &lA[t * 8];
    __hip_bfloat16* sB = &lB[t * 8];

    floatx4 acc[4][4];
    const floatx4 zero = {0.f, 0.f, 0.f, 0.f};
    #pragma unroll
    for (int i = 0; i < 4; ++i)
        #pragma unroll
        for (int j = 0; j < 4; ++j) acc[i][j] = zero;

    for (int kb = 0; kb < K_DIM; kb += 64) {
        #pragma unroll
        for (int p = 0; p < 4; ++p) {
            gld_lds16(gA[p] + kb, sA + p * 2048);
            gld_lds16(gB[p] + kb, sB + p * 2048);
        }
        __syncthreads();

        #pragma unroll
        for (int h = 0; h < 2; ++h) {
            bf16x8 af[4], bfr[4];
            #pragma unroll
            for (int i = 0; i < 4; ++i) {
                int mA = warpM * 64 + i * 16 + mrow;
                int sa = (h * 4 + quad) ^ (mA & 7);
                af[i] = *(const bf16x8*)&lA[(mA * 8 + sa) * 8];
                int mB = warpN * 64 + i * 16 + mrow;
                int sb = (h * 4 + quad) ^ (mB & 7);
                bfr[i] = *(const bf16x8*)&lB[(mB * 8 + sb) * 8];
            }
            #pragma unroll
            for (int i = 0; i < 4; ++i)
                #pragma unroll
                for (int j = 0; j < 4; ++j)
                    acc[i][j] = __builtin_amdgcn_mfma_f32_16x16x32_bf16(
                        af[i], bfr[j], acc[i][j], 0, 0, 0);
        }
        __syncthreads();
    }

    // epilogue: C/D layout col=lane&15, row=quad*4+reg  [m89/m91]
    float bj[4];
    #pragma unroll
    for (int j = 0; j < 4; ++j) bj[j] = bias[colBase + warpN * 64 + j * 16 + mrow];
    #pragma unroll
    for (int i = 0; i < 4; ++i) {
        int m0 = rowBase + warpM * 64 + i * 16 + quad * 4;
        #pragma unroll
        for (int j = 0; j < 4; ++j) {
            int n = colBase + warpN * 64 + j * 16 + mrow;
            #pragma unroll
            for (int p = 0; p < 4; ++p)
                C[(size_t)(m0 + p) * NROWS + n] = acc[i][j][p] + bj[j];
        }
    }
}

// ---------------------------------------------------------------------------
extern "C" void kernel_launch(void* const* d_in, const int* in_sizes, int n_in,
                              void* d_out, int out_size, void* d_ws, size_t ws_size,
                              hipStream_t stream) {
    const float* input  = (const float*)d_in[0];
    const float* weight = (const float*)d_in[1];
    const float* bias   = (const float*)d_in[2];
    const int*   hidx   = (const int*)d_in[3];
    const float* sgn    = (const float*)d_in[4];
    float* out = (float*)d_out;

    // workspace: sk_in 16MB | sk_w 16MB | desc 8KB | cols16 8KB
    char* ws = (char*)d_ws;
    __hip_bfloat16* sk_in = (__hip_bfloat16*)ws;
    __hip_bfloat16* sk_w  = (__hip_bfloat16*)(ws + (size_t)16 * 1024 * 1024);
    unsigned int*   desc  = (unsigned int*)(ws + (size_t)32 * 1024 * 1024);
    unsigned short* cols16 = (unsigned short*)(ws + (size_t)32 * 1024 * 1024 + 8192);

    build_csr<<<1, 256, 0, stream>>>(hidx, desc, cols16);
    sketch2<<<NROWS, 256, 0, stream>>>(input, weight, sgn, desc, cols16,
                                       sk_in, sk_w);
    gemm_bt_bias<<<dim3(32, 32), 256, 0, stream>>>(sk_in, sk_w, bias, out);
}